// Round 1
// baseline (111.384 us; speedup 1.0000x reference)
//
#include <hip/hip_runtime.h>

// DCellLinear: y[s] = x[s] @ W[s]^T + b[s], s = 0..4095
//   x: [4096, 64, 128] f32, W: [4096, 128, 128] f32 (torch Linear layout), b: [4096, 128] f32
//   out: [4096*64, 128] f32
// Memory-bound (539 MB @ ~6.3 TB/s ≈ 86 us floor). bf16 MFMA makes compute free.

typedef __attribute__((ext_vector_type(8))) short bf16x8;   // 8 bf16 = 4 VGPRs (MFMA A/B frag)
typedef __attribute__((ext_vector_type(4))) float f32x4;    // MFMA C/D frag

constexpr int NSUB = 4096;
constexpr int BATCH = 64;
constexpr int DIN = 128;
constexpr int DOUT = 128;

// f32 -> bf16 round-to-nearest-even (inputs are finite; no NaN path needed)
__device__ __forceinline__ unsigned short f2bf(float f) {
    union { float f; unsigned u; } v; v.f = f;
    unsigned r = v.u + 0x7FFFu + ((v.u >> 16) & 1u);
    return (unsigned short)(r >> 16);
}

__global__ __launch_bounds__(256, 4)
void dcell_gemm(const float* __restrict__ X, const float* __restrict__ W,
                const float* __restrict__ Bv, float* __restrict__ Y)
{
    const int s    = blockIdx.x;
    const int tid  = threadIdx.x;
    const int lane = tid & 63;
    const int qw   = lane >> 4;   // quarter-wave 0..3
    const int lr   = lane & 15;
    const int wv   = tid >> 6;    // wave 0..3

    // x tile as bf16, rows of 128 bf16 (256 B). XOR-swizzle byte^=(row&7)<<4
    // to break the stride-256B 16-way bank conflict on ds_read_b128 (G4).
    __shared__ __align__(16) unsigned short xs[BATCH * DIN];

    // ---- stage x[s] (64x128 f32 -> bf16 LDS, swizzled) ----
    const float* xsrc = X + (size_t)s * (BATCH * DIN);
    #pragma unroll
    for (int i = 0; i < 8; ++i) {
        const int idx  = tid + i * 256;     // float4 index 0..2047
        const int e    = idx * 4;           // element offset
        const int row  = e >> 7;
        const int colb = (e & 127) * 2;     // byte offset within bf16 row
        const f32x4 v  = *reinterpret_cast<const f32x4*>(xsrc + e);
        uint2 p;
        p.x = (unsigned)f2bf(v[0]) | ((unsigned)f2bf(v[1]) << 16);
        p.y = (unsigned)f2bf(v[2]) | ((unsigned)f2bf(v[3]) << 16);
        const int off = row * 256 + (colb ^ ((row & 7) << 4));
        *reinterpret_cast<uint2*>(reinterpret_cast<char*>(xs) + off) = p;
    }
    __syncthreads();

    // ---- per-wave: 32 output columns (n0..n0+31), all 64 rows ----
    const int    n0   = wv * 32;
    const float* wsrc = W  + (size_t)s * (DOUT * DIN);
    const float* bsrc = Bv + (size_t)s * DOUT;

    // C/D layout (16x16x32): col = lane&15, row = (lane>>4)*4 + reg  [m89]
    // bias depends on col only -> same value in all 4 regs; init C with it.
    f32x4 acc[4][2];
    #pragma unroll
    for (int nt = 0; nt < 2; ++nt) {
        const float bb = bsrc[n0 + nt * 16 + lr];
        #pragma unroll
        for (int mt = 0; mt < 4; ++mt) {
            acc[mt][nt][0] = bb; acc[mt][nt][1] = bb;
            acc[mt][nt][2] = bb; acc[mt][nt][3] = bb;
        }
    }

    #pragma unroll
    for (int k0 = 0; k0 < DIN; k0 += 32) {
        // B frags: lane holds W[n0+nt*16+lr][k0+qw*8 .. +7] (W is B^T layout,
        // so the k-slice is contiguous). Stream global->reg->bf16, no LDS.
        bf16x8 bfr[2];
        #pragma unroll
        for (int nt = 0; nt < 2; ++nt) {
            const float* wp = wsrc + (size_t)(n0 + nt * 16 + lr) * DIN + k0 + qw * 8;
            const f32x4 w0 = *reinterpret_cast<const f32x4*>(wp);
            const f32x4 w1 = *reinterpret_cast<const f32x4*>(wp + 4);
            bf16x8 t;
            t[0] = (short)f2bf(w0[0]); t[1] = (short)f2bf(w0[1]);
            t[2] = (short)f2bf(w0[2]); t[3] = (short)f2bf(w0[3]);
            t[4] = (short)f2bf(w1[0]); t[5] = (short)f2bf(w1[1]);
            t[6] = (short)f2bf(w1[2]); t[7] = (short)f2bf(w1[3]);
            bfr[nt] = t;
        }
        // A frags from LDS: lane holds x[mt*16+lr][k0+qw*8 .. +7]
        #pragma unroll
        for (int mt = 0; mt < 4; ++mt) {
            const int row  = mt * 16 + lr;
            const int colb = (k0 + qw * 8) * 2;
            const int off  = row * 256 + (colb ^ ((row & 7) << 4));
            const bf16x8 a = *reinterpret_cast<const bf16x8*>(
                reinterpret_cast<const char*>(xs) + off);
            #pragma unroll
            for (int nt = 0; nt < 2; ++nt)
                acc[mt][nt] = __builtin_amdgcn_mfma_f32_16x16x32_bf16(
                    a, bfr[nt], acc[mt][nt], 0, 0, 0);
        }
    }

    // ---- epilogue: fp32 stores, 16 consecutive cols per quarter-wave (64B segs)
    float* od = Y + (size_t)s * BATCH * DOUT;
    #pragma unroll
    for (int mt = 0; mt < 4; ++mt)
        #pragma unroll
        for (int nt = 0; nt < 2; ++nt)
            #pragma unroll
            for (int j = 0; j < 4; ++j) {
                const int m = mt * 16 + qw * 4 + j;
                const int c = n0 + nt * 16 + lr;
                od[m * DOUT + c] = acc[mt][nt][j];
            }
}

extern "C" void kernel_launch(void* const* d_in, const int* in_sizes, int n_in,
                              void* d_out, int out_size, void* d_ws, size_t ws_size,
                              hipStream_t stream) {
    const float* X  = (const float*)d_in[0];
    const float* W  = (const float*)d_in[1];
    const float* Bv = (const float*)d_in[2];
    float*       Y  = (float*)d_out;
    dcell_gemm<<<NSUB, 256, 0, stream>>>(X, W, Bv, Y);
}

// Round 2
// 109.309 us; speedup vs baseline: 1.0190x; 1.0190x over previous
//
#include <hip/hip_runtime.h>
#include <hip/hip_bf16.h>

// DCellLinear: y[s] = x[s] @ W[s]^T + b[s], s = 0..4095
//   x: [4096, 64, 128] f32, W: [4096, 128, 128] f32, b: [4096, 128] f32
//   out: [4096*64, 128] f32.  Memory-bound: 539 MB @ ~7 TB/s streaming => ~80 us floor.
// Structure: 1 WG / subsystem, 256 thr (4 waves). Double-buffered K-chunks (KC=32)
// of BOTH x and W staged raw-f32 via global_load_lds (fire-and-forget, deep MLP),
// f32->bf16 cvt_pk at fragment read, 16x16x32 bf16 MFMA. LDS 48 KB -> 3 blocks/CU.
// LDS rows are 128 B (KC*4); 16B-slot XOR-swizzle sl^=(row&7) applied BOTH at the
// global source (gl_lds writes linearly) and at ds_read (rule #21 involution).

typedef __attribute__((ext_vector_type(8))) short bf16x8;
typedef __attribute__((ext_vector_type(4))) float f32x4;

constexpr int NSUB = 4096, BATCH = 64, DIN = 128, DOUT = 128;
constexpr int KC = 32;                      // k-chunk (one MFMA K-step)
constexpr int XCHUNK_B = BATCH * KC * 4;    // 8 KB
constexpr int WCHUNK_B = DOUT  * KC * 4;    // 16 KB
constexpr int BUF_B    = XCHUNK_B + WCHUNK_B;

__device__ __forceinline__ unsigned pk2(float lo, float hi) {
    __hip_bfloat162 h = __float22bfloat162_rn(make_float2(lo, hi));  // v_cvt_pk_bf16_f32
    unsigned u; __builtin_memcpy(&u, &h, 4);
    return u;
}

__device__ __forceinline__ bf16x8 cvt8(f32x4 a, f32x4 b) {
    unsigned u[4];
    u[0] = pk2(a[0], a[1]); u[1] = pk2(a[2], a[3]);
    u[2] = pk2(b[0], b[1]); u[3] = pk2(b[2], b[3]);
    bf16x8 v; __builtin_memcpy(&v, u, 16);
    return v;
}

__device__ __forceinline__ void gld16(const float* g, char* l) {
    __builtin_amdgcn_global_load_lds(
        (const __attribute__((address_space(1))) unsigned*)g,
        (__attribute__((address_space(3))) unsigned*)l, 16, 0, 0);
}

__global__ __launch_bounds__(256, 3)
void dcell(const float* __restrict__ X, const float* __restrict__ W,
           const float* __restrict__ Bv, float* __restrict__ Y)
{
    __shared__ __align__(16) char lds[2][BUF_B];
    const int s    = blockIdx.x;
    const int tid  = threadIdx.x;
    const int lane = tid & 63;
    const int wv   = tid >> 6;      // wave 0..3
    const int qw   = lane >> 4;     // quarter-wave
    const int lr   = lane & 15;
    const int n0   = wv * 32;       // this wave's 32 output cols

    const float* xsrc = X + (size_t)s * BATCH * DIN;
    const float* wsrc = W + (size_t)s * DOUT * DIN;

    // Stage k-chunk t into buffer b. LDS dest is linear (gl_lds HW: base+lane*16);
    // dest 16B-slot d = blk*64+lane -> row=d>>3, sl=lane&7; source slot = sl^(row&7).
    auto stage = [&](int b, int t) {
        const int kof = t * KC;
        #pragma unroll
        for (int i = 0; i < 2; ++i) {              // x chunk: 8 KB = 8 wave-blocks
            const int blk = i * 4 + wv;
            const int row = (blk * 64 + lane) >> 3;
            const int sl  = lane & 7;
            gld16(xsrc + (size_t)row * DIN + kof + ((sl ^ (row & 7)) << 2),
                  &lds[b][blk * 1024]);
        }
        #pragma unroll
        for (int i = 0; i < 4; ++i) {              // W chunk: 16 KB = 16 wave-blocks
            const int blk = i * 4 + wv;
            const int row = (blk * 64 + lane) >> 3;
            const int sl  = lane & 7;
            gld16(wsrc + (size_t)row * DIN + kof + ((sl ^ (row & 7)) << 2),
                  &lds[b][XCHUNK_B + blk * 1024]);
        }
    };

    // Accumulators pre-loaded with bias. C/D layout (16x16x32): col=lane&15,
    // row=(lane>>4)*4+reg [m89] -> bias depends on col only.
    f32x4 acc[4][2];
    {
        const float* bs = Bv + (size_t)s * DOUT + n0;
        #pragma unroll
        for (int nt = 0; nt < 2; ++nt) {
            const float bb = bs[nt * 16 + lr];
            #pragma unroll
            for (int mt = 0; mt < 4; ++mt) {
                acc[mt][nt][0] = bb; acc[mt][nt][1] = bb;
                acc[mt][nt][2] = bb; acc[mt][nt][3] = bb;
            }
        }
    }

    stage(0, 0);
    __syncthreads();                                // drains vmcnt -> chunk 0 ready

    #pragma unroll
    for (int t = 0; t < 4; ++t) {
        const int b = t & 1;
        if (t < 3) stage(b ^ 1, t + 1);             // issue-early: hides HBM latency

        const char* xb = lds[b];
        const char* wb = lds[b] + XCHUNK_B;

        // B frags: lane holds W[n0+nt*16+lr][t*32 + qw*8 .. +7]
        bf16x8 bfr[2];
        #pragma unroll
        for (int nt = 0; nt < 2; ++nt) {
            const int row = n0 + nt * 16 + lr;
            const char* rp = wb + row * 128;
            const f32x4 lo = *(const f32x4*)(rp + (((qw * 2)     ^ (row & 7)) << 4));
            const f32x4 hi = *(const f32x4*)(rp + (((qw * 2 + 1) ^ (row & 7)) << 4));
            bfr[nt] = cvt8(lo, hi);
        }
        // A frags: lane holds x[mt*16+lr][t*32 + qw*8 .. +7]
        #pragma unroll
        for (int mt = 0; mt < 4; ++mt) {
            const int row = mt * 16 + lr;
            const char* rp = xb + row * 128;
            const f32x4 lo = *(const f32x4*)(rp + (((qw * 2)     ^ (row & 7)) << 4));
            const f32x4 hi = *(const f32x4*)(rp + (((qw * 2 + 1) ^ (row & 7)) << 4));
            const bf16x8 afr = cvt8(lo, hi);
            #pragma unroll
            for (int nt = 0; nt < 2; ++nt)
                acc[mt][nt] = __builtin_amdgcn_mfma_f32_16x16x32_bf16(
                    afr, bfr[nt], acc[mt][nt], 0, 0, 0);
        }
        __syncthreads();   // one barrier/chunk: next-chunk loads drained + buf reuse safe
    }

    // Epilogue: row m = mt*16+qw*4+j (in regs), col = n0+nt*16+lr (across lanes)
    float* od = Y + (size_t)s * BATCH * DOUT + n0;
    #pragma unroll
    for (int mt = 0; mt < 4; ++mt)
        #pragma unroll
        for (int j = 0; j < 4; ++j) {
            const int m = mt * 16 + qw * 4 + j;
            #pragma unroll
            for (int nt = 0; nt < 2; ++nt)
                od[(size_t)m * DOUT + nt * 16 + lr] = acc[mt][nt][j];
        }
}

extern "C" void kernel_launch(void* const* d_in, const int* in_sizes, int n_in,
                              void* d_out, int out_size, void* d_ws, size_t ws_size,
                              hipStream_t stream) {
    const float* X  = (const float*)d_in[0];
    const float* W  = (const float*)d_in[1];
    const float* Bv = (const float*)d_in[2];
    float*       Y  = (float*)d_out;
    dcell<<<NSUB, 256, 0, stream>>>(X, W, Bv, Y);
}

// Round 3
// 108.251 us; speedup vs baseline: 1.0289x; 1.0098x over previous
//
#include <hip/hip_runtime.h>
#include <hip/hip_bf16.h>

// DCellLinear: y[s] = x[s] @ W[s]^T + b[s], s = 0..4095 (all f32, bf16 MFMA inside)
// Memory-bound: 539 MB irreducible @ ~6.3 TB/s => ~86 us floor.
// R3 structure: 1 WG/subsystem, 256 thr. Fully-LINEAR global reads (x 32KB + W 64KB
// contiguous dwordx4 bursts) -> in-reg cvt_pk f32->bf16 -> single-shot LDS panels
// (x 16KB + W 32KB, XOR-swizzled rows) -> 1 barrier -> 4 MFMA k-steps from LDS ->
// LDS-bounce accumulator transpose -> 8 fully-linear global_store_dwordx4/thread.
// 3 barriers/block, no K-strided global access, no per-chunk vmcnt drains.

typedef __attribute__((ext_vector_type(8))) short bf16x8;
typedef __attribute__((ext_vector_type(4))) float f32x4;

constexpr int NSUB = 4096, BATCH = 64, DIN = 128, DOUT = 128;
constexpr int XOFF = 0;        // x panel [64 rows][256 B bf16]  = 16 KB
constexpr int WOFF = 16384;    // W panel [128 rows][256 B bf16] = 32 KB
// epilogue (after reuse barrier): per-wave f32 slab [64][36] = 9216 B at wv*9216

__device__ __forceinline__ unsigned pk2(float lo, float hi) {
    __hip_bfloat162 h = __float22bfloat162_rn(make_float2(lo, hi));  // v_cvt_pk_bf16_f32
    unsigned u; __builtin_memcpy(&u, &h, 4);
    return u;
}

__global__ __launch_bounds__(256, 3)
void dcell(const float* __restrict__ X, const float* __restrict__ W,
           const float* __restrict__ Bv, float* __restrict__ Y)
{
    __shared__ __align__(16) char lds[49152];
    const int s    = blockIdx.x;
    const int tid  = threadIdx.x;
    const int lane = tid & 63;
    const int wv   = tid >> 6;
    const int qw   = lane >> 4;
    const int lr   = lane & 15;
    const int n0   = wv * 32;          // wave's 32 output cols

    const float* xsrc = X + (size_t)s * (BATCH * DIN);
    const float* wsrc = W + (size_t)s * (DOUT * DIN);

    // ---- issue ALL global reads as linear bursts (1 KB/wave-instr) ----
    f32x4 xr[8], wr[16];
    #pragma unroll
    for (int i = 0; i < 8; ++i)
        xr[i] = *reinterpret_cast<const f32x4*>(xsrc + 4 * (tid + 256 * i));
    #pragma unroll
    for (int i = 0; i < 16; ++i)
        wr[i] = *reinterpret_cast<const f32x4*>(wsrc + 4 * (tid + 256 * i));

    // ---- bias -> accumulators (C/D: col=lane&15, row=qw*4+reg [m89]) ----
    f32x4 acc[4][2];
    {
        const float* bs = Bv + (size_t)s * DOUT + n0;
        #pragma unroll
        for (int nt = 0; nt < 2; ++nt) {
            const float bb = bs[nt * 16 + lr];
            #pragma unroll
            for (int mt = 0; mt < 4; ++mt) {
                acc[mt][nt][0] = bb; acc[mt][nt][1] = bb;
                acc[mt][nt][2] = bb; acc[mt][nt][3] = bb;
            }
        }
    }

    // ---- cvt f32->bf16, write swizzled panels (byte ^= (row&7)<<4, R1-verified) ----
    #pragma unroll
    for (int i = 0; i < 8; ++i) {
        const int c = tid + 256 * i, row = c >> 5, colb = (c & 31) * 8;
        uint2 p; p.x = pk2(xr[i][0], xr[i][1]); p.y = pk2(xr[i][2], xr[i][3]);
        *reinterpret_cast<uint2*>(lds + XOFF + row * 256 + (colb ^ ((row & 7) << 4))) = p;
    }
    #pragma unroll
    for (int i = 0; i < 16; ++i) {
        const int c = tid + 256 * i, row = c >> 5, colb = (c & 31) * 8;
        uint2 p; p.x = pk2(wr[i][0], wr[i][1]); p.y = pk2(wr[i][2], wr[i][3]);
        *reinterpret_cast<uint2*>(lds + WOFF + row * 256 + (colb ^ ((row & 7) << 4))) = p;
    }
    __syncthreads();

    // ---- 4 MFMA k-steps, all operands from LDS ----
    #pragma unroll
    for (int k0 = 0; k0 < DIN; k0 += 32) {
        bf16x8 bfr[2];
        #pragma unroll
        for (int nt = 0; nt < 2; ++nt) {
            const int row = n0 + nt * 16 + lr;
            const int colb = ((k0 + qw * 8) * 2) ^ ((row & 7) << 4);
            bfr[nt] = *reinterpret_cast<const bf16x8*>(lds + WOFF + row * 256 + colb);
        }
        #pragma unroll
        for (int mt = 0; mt < 4; ++mt) {
            const int row = mt * 16 + lr;
            const int colb = ((k0 + qw * 8) * 2) ^ ((row & 7) << 4);
            const bf16x8 afr = *reinterpret_cast<const bf16x8*>(lds + XOFF + row * 256 + colb);
            #pragma unroll
            for (int nt = 0; nt < 2; ++nt)
                acc[mt][nt] = __builtin_amdgcn_mfma_f32_16x16x32_bf16(
                    afr, bfr[nt], acc[mt][nt], 0, 0, 0);
        }
    }
    __syncthreads();   // panels dead; LDS reused for accumulator transpose

    // ---- acc -> per-wave f32 slab [64][36] (pad 4 kills write conflicts) ----
    float* slab = reinterpret_cast<float*>(lds) + wv * 2304;
    #pragma unroll
    for (int mt = 0; mt < 4; ++mt)
        #pragma unroll
        for (int j = 0; j < 4; ++j) {
            const int row = mt * 16 + qw * 4 + j;
            #pragma unroll
            for (int nt = 0; nt < 2; ++nt)
                slab[row * 36 + nt * 16 + lr] = acc[mt][nt][j];
        }
    __syncthreads();

    // ---- fully-linear vectorized stores: 32 KB contiguous per block ----
    float* od = Y + (size_t)s * (BATCH * DOUT);
    const float* lf = reinterpret_cast<const float*>(lds);
    #pragma unroll
    for (int i = 0; i < 8; ++i) {
        const int c = tid + 256 * i;            // f32x4 chunk in [64][128]
        const int row = c >> 5, col4 = (c & 31) * 4;
        const f32x4 v = *reinterpret_cast<const f32x4*>(
            lf + (col4 >> 5) * 2304 + row * 36 + (col4 & 31));
        *reinterpret_cast<f32x4*>(od + 4 * c) = v;
    }
}

extern "C" void kernel_launch(void* const* d_in, const int* in_sizes, int n_in,
                              void* d_out, int out_size, void* d_ws, size_t ws_size,
                              hipStream_t stream) {
    const float* X  = (const float*)d_in[0];
    const float* W  = (const float*)d_in[1];
    const float* Bv = (const float*)d_in[2];
    float*       Y  = (float*)d_out;
    dcell<<<NSUB, 256, 0, stream>>>(X, W, Bv, Y);
}